// Round 3
// baseline (46948.087 us; speedup 1.0000x reference)
//
#include <hip/hip_runtime.h>
#include <hip/hip_bf16.h>

#define TT 800
#define BB 32

typedef unsigned short ushort_t;
using bf16x8 = __attribute__((ext_vector_type(8))) short;
using f32x4  = __attribute__((ext_vector_type(4))) float;

// ---------------- workspace layout ----------------
#define OFF_AP   0ULL                  // 25600*3072*2   = 157286400
#define OFF_BT   157286400ULL          // 4096*3072*2    =  25165824
#define OFF_XG   182452224ULL          // 2*800*32*2048*4= 419430400
#define OFF_WRP  601882624ULL          // 4*2048*1536*2  =  25165824
#define OFF_HF   627048448ULL          // 4*49152*2      =    393216
#define OFF_BARR 627441664ULL          // 1024
#define WS_TOTAL 627442688ULL

// Static fallback workspace: allocated at module load => graph-capture safe.
__device__ char g_ws[WS_TOTAL];

// ---------------- helpers ----------------
__device__ __forceinline__ ushort_t bf_hi(float v) {
  __hip_bfloat16 h = __float2bfloat16(v);
  return __builtin_bit_cast(ushort_t, h);
}
__device__ __forceinline__ float bf_f(ushort_t u) {
  __hip_bfloat16 h = __builtin_bit_cast(__hip_bfloat16, u);
  return __bfloat162float(h);
}
__device__ __forceinline__ float sigf(float x)      { return 1.0f / (1.0f + __expf(-x)); }
__device__ __forceinline__ float tanh_fast(float x) { return 2.0f / (1.0f + __expf(-2.0f*x)) - 1.0f; }

__device__ __forceinline__ void gload16(const void* g, void* l) {
  __builtin_amdgcn_global_load_lds((const __attribute__((address_space(1))) void*)g,
                                   (__attribute__((address_space(3))) void*)l,
                                   16, 0, 0);
}

// ---------------- fp32 -> (hi,lo,hi) bf16 K-interleave for A ----------------
// src [M][K] fp32 -> dst [M][3K] bf16 (row-contiguous)
__global__ __launch_bounds__(256) void splitA(const float* __restrict__ src,
                                              ushort_t* __restrict__ dst,
                                              long long total) {
  long long idx = (long long)blockIdx.x * 256 + threadIdx.x;
  if (idx >= total) return;
  float4 v = ((const float4*)src)[idx];
  float vs[4] = {v.x, v.y, v.z, v.w};
  ushort_t o[12];
#pragma unroll
  for (int e = 0; e < 4; ++e) {
    ushort_t hi = bf_hi(vs[e]);
    ushort_t lo = bf_hi(vs[e] - bf_f(hi));
    o[3*e] = hi; o[3*e+1] = lo; o[3*e+2] = hi;
  }
  ushort4* dp = (ushort4*)(dst + 12*idx);
  dp[0] = make_ushort4(o[0], o[1], o[2], o[3]);
  dp[1] = make_ushort4(o[4], o[5], o[6], o[7]);
  dp[2] = make_ushort4(o[8], o[9], o[10], o[11]);
}

// ---------------- fp32 [K][N] -> bf16 [n][3K] transposed split for B ----------------
// per k: [3k]=hi (pairs a_hi), [3k+1]=hi (pairs a_lo), [3k+2]=lo (pairs a_hi)
__global__ __launch_bounds__(256) void splitBT(const float* __restrict__ src,
                                               ushort_t* __restrict__ dst,
                                               int srcPitch, int Nvalid, int dstPitch) {
  __shared__ float tile[32][33];
  int k0 = blockIdx.x * 32, n0 = blockIdx.y * 32;
  int tx = threadIdx.x, ty = threadIdx.y;   // (32,8)
#pragma unroll
  for (int i = 0; i < 4; ++i) {
    int k = k0 + ty + i*8;
    int n = n0 + tx;
    float v = 0.f;
    if (n < Nvalid) v = src[(long long)k * srcPitch + n];
    tile[ty + i*8][tx] = v;
  }
  __syncthreads();
#pragma unroll
  for (int q = 0; q < 4; ++q) {
    int kk = ty*4 + q;
    float v = tile[kk][tx];
    ushort_t hi = bf_hi(v);
    ushort_t lo = bf_hi(v - bf_f(hi));
    long long off = (long long)(n0 + tx) * dstPitch + 3*(k0 + kk);
    dst[off] = hi; dst[off+1] = hi; dst[off+2] = lo;
  }
}

// ---------------- split-bf16 GEMM (m97-style, 128x128 tile, BK=32) ----------------
// A [M][Kp] bf16 row-major, Bt [N][Kp] bf16 row-major (B^T), fp32 acc.
// mode 0: out = xg, layout [d][t][b][u*4+g] (unit-major cols), bias by original col.
// mode 1: out[m*80+n] for n<80, bias0.
__global__ __launch_bounds__(256) void gemm_split(
    const ushort_t* __restrict__ A, const ushort_t* __restrict__ Bt,
    float* __restrict__ out, const float* __restrict__ bias0,
    const float* __restrict__ bias1, int Kp, int mode)
{
  __shared__ ushort_t As[128*32];
  __shared__ ushort_t Bs[128*32];
  const int tid  = threadIdx.x;
  const int lane = tid & 63, wid = tid >> 6;
  const int m0 = blockIdx.y * 128, n0 = blockIdx.x * 128;
  const int wm = (wid >> 1) * 64, wn = (wid & 1) * 64;
  const int frow = lane & 15, fkg = (lane >> 4) * 8;

  f32x4 acc[4][4] = {};

  for (int k0 = 0; k0 < Kp; k0 += 32) {
#pragma unroll
    for (int i = 0; i < 2; ++i) {
      int c = tid + i*256;
      int r = c >> 2, co = (c & 3) * 8;
      gload16(A  + (size_t)(m0 + r) * Kp + k0 + co, (void*)(As + c*8));
      gload16(Bt + (size_t)(n0 + r) * Kp + k0 + co, (void*)(Bs + c*8));
    }
    __syncthreads();
    bf16x8 af[4], bq[4];
#pragma unroll
    for (int f = 0; f < 4; ++f) {
      af[f] = *(const bf16x8*)(As + (wm + f*16 + frow)*32 + fkg);
      bq[f] = *(const bf16x8*)(Bs + (wn + f*16 + frow)*32 + fkg);
    }
#pragma unroll
    for (int mf = 0; mf < 4; ++mf)
#pragma unroll
      for (int nf = 0; nf < 4; ++nf)
        acc[mf][nf] = __builtin_amdgcn_mfma_f32_16x16x32_bf16(af[mf], bq[nf], acc[mf][nf], 0, 0, 0);
    __syncthreads();
  }

  const int r4 = (lane >> 4) * 4, ccol = lane & 15;
#pragma unroll
  for (int mf = 0; mf < 4; ++mf)
#pragma unroll
    for (int nf = 0; nf < 4; ++nf) {
#pragma unroll
      for (int j = 0; j < 4; ++j) {
        int m = m0 + wm + mf*16 + r4 + j;
        int n = n0 + wn + nf*16 + ccol;
        float v = acc[mf][nf][j];
        int t = m % TT, b = m / TT;
        if (mode == 0) {
          int d2 = n >> 11, n2 = n & 2047, g = n2 >> 9, u2 = n2 & 511;
          v += (d2 == 0 ? bias0[n2] : bias1[n2]);
          out[(((size_t)d2*TT + t)*BB + b)*2048 + u2*4 + g] = v;
        } else {
          if (n < 80) out[(size_t)m*80 + n] = v + bias0[n];
        }
      }
    }
}

// ---------------- persistent bidirectional LSTM layer (MFMA recurrence) ----------------
// 256 WGs x 256 thr. WG w: dir d=w>>7, unit-block u0=(w&127)*4 -> 16 gate cols
// gc(c)=(c>>2)*512+u0+(c&3). 4 waves split K'=1536 into quarters; Wr' fragments
// live in VGPRs for all 800 steps. h' (split-bf16) is exchanged in MFMA
// fragment order through global double buffers; per-direction grid barrier.
__global__ __launch_bounds__(256) void lstm_layer(
    const float* __restrict__ xg, const ushort_t* __restrict__ wrp,
    const int* __restrict__ lens, ushort_t* __restrict__ Aout,
    ushort_t* __restrict__ hfrag, int* __restrict__ barr)
{
  const int w   = blockIdx.x;
  const int d   = w >> 7;
  const int u0  = (w & 127) * 4;
  const int tid = threadIdx.x;
  const int q    = tid >> 6;         // wave = K'-quarter
  const int lane = tid & 63;
  const int c    = lane & 15;        // local col 0..15 (g=c>>2, j=c&3)
  const int kg   = lane >> 4;        // k-subgroup 0..3
  const int gc   = (c >> 2) * 512 + u0 + (c & 3);

  __shared__ float pz[32][16][5];    // [b][c][kq-partial] (+1 pad)
  __shared__ float cbuf[32][4];
  __shared__ float hpb[32][4];
  __shared__ int   lenS[32];

  if (tid < 32)  lenS[tid] = lens[tid];
  if (tid < 128) { cbuf[tid >> 2][tid & 3] = 0.f; hpb[tid >> 2][tid & 3] = 0.f; }

  // ---- load weight B-fragments once: wave q holds K'-range [384q, 384q+384) ----
  bf16x8 wfrag[12];
  {
    const ushort_t* wr = wrp + (size_t)d * 2048 * 1536 + (size_t)gc * 1536;
#pragma unroll
    for (int ktl = 0; ktl < 12; ++ktl)
      wfrag[ktl] = *(const bf16x8*)(wr + (12*q + ktl)*32 + kg*8);
  }
  __syncthreads();

  int* bbase = barr + d*16;          // [0..7]=group counters, [8]=rc, [9]=sense
  const int grp = (w & 127) >> 4;

  for (int s = 0; s < TT; ++s) {
    const int t = d ? (TT - 1 - s) : s;
    const int cur = s & 1, nxt = cur ^ 1;

    // ---- A-fragments direct from global h' (fragment-order layout) ----
    const ushort_t* hf = hfrag + (size_t)(d*2 + cur) * 49152;
    bf16x8 a0[12], a1[12];
#pragma unroll
    for (int ktl = 0; ktl < 12; ++ktl) {
      int kt = 12*q + ktl;
      a0[ktl] = *(const bf16x8*)(hf + ((size_t)(0*48 + kt)*64 + lane)*8);
      a1[ktl] = *(const bf16x8*)(hf + ((size_t)(1*48 + kt)*64 + lane)*8);
    }
    f32x4 acc0 = {0.f,0.f,0.f,0.f}, acc1 = {0.f,0.f,0.f,0.f};
#pragma unroll
    for (int ktl = 0; ktl < 12; ++ktl) {
      acc0 = __builtin_amdgcn_mfma_f32_16x16x32_bf16(a0[ktl], wfrag[ktl], acc0, 0, 0, 0);
      acc1 = __builtin_amdgcn_mfma_f32_16x16x32_bf16(a1[ktl], wfrag[ktl], acc1, 0, 0, 0);
    }
    // C/D: col=lane&15=c, row=kg*4+j (+16 for second M-tile)
#pragma unroll
    for (int j = 0; j < 4; ++j) {
      pz[kg*4 + j][c][q]      = acc0[j];
      pz[16 + kg*4 + j][c][q] = acc1[j];
    }
    __syncthreads();

    if (tid < 128) {
      const int b2 = tid >> 2, j = tid & 3;
      const int u = u0 + j;
      float z[4];
#pragma unroll
      for (int g = 0; g < 4; ++g) {
        const int cc = g*4 + j;
        z[g] = ((pz[b2][cc][0] + pz[b2][cc][1]) + (pz[b2][cc][2] + pz[b2][cc][3]));
      }
      const float4 xv = *(const float4*)(xg + (((size_t)d*TT + t)*BB + b2)*2048 + (size_t)u*4);
      const float zi = z[0] + xv.x, zf = z[1] + xv.y, zc = z[2] + xv.z, zo = z[3] + xv.w;
      const float co = cbuf[b2][j];
      const float cn = sigf(zf)*co + sigf(zi)*tanh_fast(zc);
      const float hn = sigf(zo)*tanh_fast(cn);
      const float hp = hpb[b2][j];
      const bool  mk = t < lenS[b2];
      const float h2 = mk ? hn : hp;
      const float c2 = mk ? cn : co;
      cbuf[b2][j] = c2; hpb[b2][j] = h2;

      const ushort_t hi = bf_hi(h2);
      const ushort_t lo = bf_hi(h2 - bf_f(hi));
      // split-A triplets for the next GEMM: row m=b*800+t, k=d*512+u, K=1024
      {
        size_t ab = 3ULL * ((size_t)(b2*TT + t)*1024 + (d*512 + u));
        Aout[ab] = hi; Aout[ab+1] = lo; Aout[ab+2] = hi;
      }
      // h' fragment-order triplets for step s+1
      {
        ushort_t* hfn = hfrag + (size_t)(d*2 + nxt) * 49152;
        const int r = b2 & 15, mt = b2 >> 4;
#pragma unroll
        for (int jj = 0; jj < 3; ++jj) {
          const int kp = 3*u + jj;
          const int kt = kp >> 5, kg2 = (kp >> 3) & 3, e = kp & 7;
          hfn[((size_t)(mt*48 + kt)*64 + kg2*16 + r)*8 + e] = (jj == 1) ? lo : hi;
        }
      }
    }
    __syncthreads();

    // ---- per-direction grid barrier (two-level monotonic, acq_rel chain) ----
    if (tid == 0) {
      int v = __hip_atomic_fetch_add(&bbase[grp], 1, __ATOMIC_ACQ_REL, __HIP_MEMORY_SCOPE_AGENT) + 1;
      bool rel = false;
      if (v == 16*(s+1)) {
        int r = __hip_atomic_fetch_add(&bbase[8], 1, __ATOMIC_ACQ_REL, __HIP_MEMORY_SCOPE_AGENT) + 1;
        if (r == 8*(s+1)) {
          __hip_atomic_store(&bbase[9], s+1, __ATOMIC_RELEASE, __HIP_MEMORY_SCOPE_AGENT);
          rel = true;
        }
      }
      if (!rel) {
        while (__hip_atomic_load(&bbase[9], __ATOMIC_RELAXED, __HIP_MEMORY_SCOPE_AGENT) < s+1)
          __builtin_amdgcn_s_sleep(2);
      }
      __threadfence();
    }
    __syncthreads();
  }
}

// ---------------- launch ----------------
extern "C" void kernel_launch(void* const* d_in, const int* in_sizes, int n_in,
                              void* d_out, int out_size, void* d_ws, size_t ws_size,
                              hipStream_t stream) {
  const float* x    = (const float*)d_in[0];
  const int*   lens = (const int*)d_in[1];
  const float* Wk1f = (const float*)d_in[2];
  const float* Wr1f = (const float*)d_in[3];
  const float* b1f  = (const float*)d_in[4];
  const float* Wk1b = (const float*)d_in[5];
  const float* Wr1b = (const float*)d_in[6];
  const float* b1b  = (const float*)d_in[7];
  const float* Wk2f = (const float*)d_in[8];
  const float* Wr2f = (const float*)d_in[9];
  const float* b2f  = (const float*)d_in[10];
  const float* Wk2b = (const float*)d_in[11];
  const float* Wr2b = (const float*)d_in[12];
  const float* b2b  = (const float*)d_in[13];
  const float* pW   = (const float*)d_in[14];
  const float* pb   = (const float*)d_in[15];
  float* out = (float*)d_out;

  char* base = (char*)d_ws;
  if (ws_size < WS_TOTAL) {
    void* p = nullptr;
    hipGetSymbolAddress(&p, HIP_SYMBOL(g_ws));
    base = (char*)p;
  }

  ushort_t* Ap  = (ushort_t*)(base + OFF_AP);
  ushort_t* Bt  = (ushort_t*)(base + OFF_BT);
  float*    XG  = (float*)(base + OFF_XG);
  ushort_t* WRP = (ushort_t*)(base + OFF_WRP);
  ushort_t* HF  = (ushort_t*)(base + OFF_HF);
  int*      BARR= (int*)(base + OFF_BARR);

  dim3 tb32x8(32, 8, 1);

  // recurrent-weight split transpose: Wr [512][2048] -> Wr' [2048][1536]
  splitBT<<<dim3(16,64), tb32x8, 0, stream>>>(Wr1f, WRP,              2048, 2048, 1536);
  splitBT<<<dim3(16,64), tb32x8, 0, stream>>>(Wr1b, WRP + 3145728,    2048, 2048, 1536);
  splitBT<<<dim3(16,64), tb32x8, 0, stream>>>(Wr2f, WRP + 2*3145728,  2048, 2048, 1536);
  splitBT<<<dim3(16,64), tb32x8, 0, stream>>>(Wr2b, WRP + 3*3145728,  2048, 2048, 1536);

  // ---- layer 1 ----
  splitA<<<14400, 256, 0, stream>>>(x, Ap, 3686400LL);                       // K=576 -> 1728
  splitBT<<<dim3(18,64), tb32x8, 0, stream>>>(Wk1f, Bt,               2048, 2048, 1728);
  splitBT<<<dim3(18,64), tb32x8, 0, stream>>>(Wk1b, Bt + 2048LL*1728, 2048, 2048, 1728);
  gemm_split<<<dim3(32,200), 256, 0, stream>>>(Ap, Bt, XG, b1f, b1b, 1728, 0);
  hipMemsetAsync(base + OFF_HF, 0, WS_TOTAL - OFF_HF, stream);
  lstm_layer<<<256, 256, 0, stream>>>(XG, WRP, lens, Ap, HF, BARR);          // writes H1 triplets (K=1024->3072)

  // ---- layer 2 ----
  splitBT<<<dim3(32,64), tb32x8, 0, stream>>>(Wk2f, Bt,               2048, 2048, 3072);
  splitBT<<<dim3(32,64), tb32x8, 0, stream>>>(Wk2b, Bt + 2048LL*3072, 2048, 2048, 3072);
  gemm_split<<<dim3(32,200), 256, 0, stream>>>(Ap, Bt, XG, b2f, b2b, 3072, 0);
  hipMemsetAsync(base + OFF_HF, 0, WS_TOTAL - OFF_HF, stream);
  lstm_layer<<<256, 256, 0, stream>>>(XG, WRP + 2*3145728, lens, Ap, HF, BARR); // writes H2 triplets

  // ---- projection ----
  splitBT<<<dim3(32,4), tb32x8, 0, stream>>>(pW, Bt, 80, 80, 3072);          // pad N to 128
  gemm_split<<<dim3(1,200), 256, 0, stream>>>(Ap, Bt, out, pb, nullptr, 3072, 1);
}

// Round 4
// 34696.481 us; speedup vs baseline: 1.3531x; 1.3531x over previous
//
#include <hip/hip_runtime.h>
#include <hip/hip_bf16.h>

#define TT 800
#define BB 32

typedef unsigned short ushort_t;
using bf16x8 = __attribute__((ext_vector_type(8))) short;
using f32x4  = __attribute__((ext_vector_type(4))) float;

// ---------------- workspace layout ----------------
#define OFF_AP   0ULL                  // 25600*3072*2   = 157286400
#define OFF_BT   157286400ULL          // 4096*3072*2    =  25165824
#define OFF_XG   182452224ULL          // 2*800*32*2048*4= 419430400
#define OFF_WRP  601882624ULL          // 4*2048*1536*2  =  25165824
#define OFF_HF   627048448ULL          // 4*49152*2      =    393216
#define OFF_BARR 627441664ULL          // 1024
#define WS_TOTAL 627442688ULL

// Static fallback workspace: allocated at module load => graph-capture safe.
__device__ char g_ws[WS_TOTAL];

// ---------------- helpers ----------------
__device__ __forceinline__ ushort_t bf_hi(float v) {
  __hip_bfloat16 h = __float2bfloat16(v);
  return __builtin_bit_cast(ushort_t, h);
}
__device__ __forceinline__ float bf_f(ushort_t u) {
  __hip_bfloat16 h = __builtin_bit_cast(__hip_bfloat16, u);
  return __bfloat162float(h);
}
__device__ __forceinline__ float sigf(float x)      { return 1.0f / (1.0f + __expf(-x)); }
__device__ __forceinline__ float tanh_fast(float x) { return 2.0f / (1.0f + __expf(-2.0f*x)) - 1.0f; }

__device__ __forceinline__ void gload16(const void* g, void* l) {
  __builtin_amdgcn_global_load_lds((const __attribute__((address_space(1))) void*)g,
                                   (__attribute__((address_space(3))) void*)l,
                                   16, 0, 0);
}

// ---------------- fp32 -> (hi,lo,hi) bf16 K-interleave for A ----------------
__global__ __launch_bounds__(256) void splitA(const float* __restrict__ src,
                                              ushort_t* __restrict__ dst,
                                              long long total) {
  long long idx = (long long)blockIdx.x * 256 + threadIdx.x;
  if (idx >= total) return;
  float4 v = ((const float4*)src)[idx];
  float vs[4] = {v.x, v.y, v.z, v.w};
  ushort_t o[12];
#pragma unroll
  for (int e = 0; e < 4; ++e) {
    ushort_t hi = bf_hi(vs[e]);
    ushort_t lo = bf_hi(vs[e] - bf_f(hi));
    o[3*e] = hi; o[3*e+1] = lo; o[3*e+2] = hi;
  }
  ushort4* dp = (ushort4*)(dst + 12*idx);
  dp[0] = make_ushort4(o[0], o[1], o[2], o[3]);
  dp[1] = make_ushort4(o[4], o[5], o[6], o[7]);
  dp[2] = make_ushort4(o[8], o[9], o[10], o[11]);
}

// ---------------- fp32 [K][N] -> bf16 [n][3K] transposed split for B ----------------
__global__ __launch_bounds__(256) void splitBT(const float* __restrict__ src,
                                               ushort_t* __restrict__ dst,
                                               int srcPitch, int Nvalid, int dstPitch) {
  __shared__ float tile[32][33];
  int k0 = blockIdx.x * 32, n0 = blockIdx.y * 32;
  int tx = threadIdx.x, ty = threadIdx.y;   // (32,8)
#pragma unroll
  for (int i = 0; i < 4; ++i) {
    int k = k0 + ty + i*8;
    int n = n0 + tx;
    float v = 0.f;
    if (n < Nvalid) v = src[(long long)k * srcPitch + n];
    tile[ty + i*8][tx] = v;
  }
  __syncthreads();
#pragma unroll
  for (int q = 0; q < 4; ++q) {
    int kk = ty*4 + q;
    float v = tile[kk][tx];
    ushort_t hi = bf_hi(v);
    ushort_t lo = bf_hi(v - bf_f(hi));
    long long off = (long long)(n0 + tx) * dstPitch + 3*(k0 + kk);
    dst[off] = hi; dst[off+1] = hi; dst[off+2] = lo;
  }
}

// ---------------- split-bf16 GEMM (m97-style, 128x128 tile, BK=32) ----------------
__global__ __launch_bounds__(256) void gemm_split(
    const ushort_t* __restrict__ A, const ushort_t* __restrict__ Bt,
    float* __restrict__ out, const float* __restrict__ bias0,
    const float* __restrict__ bias1, int Kp, int mode)
{
  __shared__ ushort_t As[128*32];
  __shared__ ushort_t Bs[128*32];
  const int tid  = threadIdx.x;
  const int lane = tid & 63, wid = tid >> 6;
  const int m0 = blockIdx.y * 128, n0 = blockIdx.x * 128;
  const int wm = (wid >> 1) * 64, wn = (wid & 1) * 64;
  const int frow = lane & 15, fkg = (lane >> 4) * 8;

  f32x4 acc[4][4] = {};

  for (int k0 = 0; k0 < Kp; k0 += 32) {
#pragma unroll
    for (int i = 0; i < 2; ++i) {
      int c = tid + i*256;
      int r = c >> 2, co = (c & 3) * 8;
      gload16(A  + (size_t)(m0 + r) * Kp + k0 + co, (void*)(As + c*8));
      gload16(Bt + (size_t)(n0 + r) * Kp + k0 + co, (void*)(Bs + c*8));
    }
    __syncthreads();
    bf16x8 af[4], bq[4];
#pragma unroll
    for (int f = 0; f < 4; ++f) {
      af[f] = *(const bf16x8*)(As + (wm + f*16 + frow)*32 + fkg);
      bq[f] = *(const bf16x8*)(Bs + (wn + f*16 + frow)*32 + fkg);
    }
#pragma unroll
    for (int mf = 0; mf < 4; ++mf)
#pragma unroll
      for (int nf = 0; nf < 4; ++nf)
        acc[mf][nf] = __builtin_amdgcn_mfma_f32_16x16x32_bf16(af[mf], bq[nf], acc[mf][nf], 0, 0, 0);
    __syncthreads();
  }

  const int r4 = (lane >> 4) * 4, ccol = lane & 15;
#pragma unroll
  for (int mf = 0; mf < 4; ++mf)
#pragma unroll
    for (int nf = 0; nf < 4; ++nf) {
#pragma unroll
      for (int j = 0; j < 4; ++j) {
        int m = m0 + wm + mf*16 + r4 + j;
        int n = n0 + wn + nf*16 + ccol;
        float v = acc[mf][nf][j];
        int t = m % TT, b = m / TT;
        if (mode == 0) {
          int d2 = n >> 11, n2 = n & 2047, g = n2 >> 9, u2 = n2 & 511;
          v += (d2 == 0 ? bias0[n2] : bias1[n2]);
          out[(((size_t)d2*TT + t)*BB + b)*2048 + u2*4 + g] = v;
        } else {
          if (n < 80) out[(size_t)m*80 + n] = v + bias0[n];
        }
      }
    }
}

// ---------------- persistent bidirectional LSTM layer (MFMA recurrence) ----------------
// 256 WGs x 256 thr. WG w: dir d=w>>7, unit-block u0=(w&127)*4 -> 16 gate cols.
// Wave q owns K'-quarter; Wr' fragments live in VGPRs for all 800 steps.
// launch_bounds(256,2): VGPR cap 256 -> all 24 A-frag loads resident & issued
// before the MFMA block (was 80 VGPR -> serialized load-use chains, 28us/step).
__global__ __launch_bounds__(256, 2) void lstm_layer(
    const float* __restrict__ xg, const ushort_t* __restrict__ wrp,
    const int* __restrict__ lens, ushort_t* __restrict__ Aout,
    ushort_t* __restrict__ hfrag, int* __restrict__ barr)
{
  const int w   = blockIdx.x;
  const int d   = w >> 7;
  const int u0  = (w & 127) * 4;
  const int tid = threadIdx.x;
  const int q    = tid >> 6;         // wave = K'-quarter
  const int lane = tid & 63;
  const int c    = lane & 15;        // local col 0..15 (g=c>>2, j=c&3)
  const int kg   = lane >> 4;        // k-subgroup 0..3
  const int gc   = (c >> 2) * 512 + u0 + (c & 3);

  __shared__ float pz[32][16][5];    // [b][c][kq-partial] (+1 pad)
  __shared__ float cbuf[32][4];
  __shared__ float hpb[32][4];
  __shared__ int   lenS[32];

  if (tid < 32)  lenS[tid] = lens[tid];
  if (tid < 128) { cbuf[tid >> 2][tid & 3] = 0.f; hpb[tid >> 2][tid & 3] = 0.f; }

  // ---- load weight B-fragments once: wave q holds K'-range [384q, 384q+384) ----
  bf16x8 wfrag[12];
  {
    const ushort_t* wr = wrp + (size_t)d * 2048 * 1536 + (size_t)gc * 1536;
#pragma unroll
    for (int ktl = 0; ktl < 12; ++ktl)
      wfrag[ktl] = *(const bf16x8*)(wr + (12*q + ktl)*32 + kg*8);
  }
  __syncthreads();

  // barrier region: direction d at barr+d*128 ints (512B apart);
  // 8 group counters 32B apart, rc at +320B, sense at +384B.
  int* bb = barr + d*128;
  const int grp = (w & 127) >> 4;
  int* gcnt  = bb + grp*8;
  int* rc    = bb + 80;
  int* sense = bb + 96;

  // gate-phase thread mapping (tid<128): b2, j, global unit u
  const int b2 = tid >> 2, j = tid & 3;
  const int u  = u0 + j;
  // prefetch xv for step 0
  float4 xv = {0.f,0.f,0.f,0.f};
  if (tid < 128) {
    const int t0 = d ? (TT-1) : 0;
    xv = *(const float4*)(xg + (((size_t)d*TT + t0)*BB + b2)*2048 + (size_t)u*4);
  }

  for (int s = 0; s < TT; ++s) {
    const int t = d ? (TT - 1 - s) : s;
    const int cur = s & 1, nxt = cur ^ 1;

    // ---- A-fragments direct from global h' (fragment-order layout) ----
    const ushort_t* hf = hfrag + (size_t)(d*2 + cur) * 49152;
    const ushort_t* p0 = hf + ((size_t)(12*q)*64 + lane)*8;
    bf16x8 a0[12], a1[12];
#pragma unroll
    for (int ktl = 0; ktl < 12; ++ktl) {
      a0[ktl] = *(const bf16x8*)(p0 + ktl*512);
      a1[ktl] = *(const bf16x8*)(p0 + 24576 + ktl*512);
    }
    f32x4 acc0 = {0.f,0.f,0.f,0.f}, acc1 = {0.f,0.f,0.f,0.f};
#pragma unroll
    for (int ktl = 0; ktl < 12; ++ktl) {
      acc0 = __builtin_amdgcn_mfma_f32_16x16x32_bf16(a0[ktl], wfrag[ktl], acc0, 0, 0, 0);
      acc1 = __builtin_amdgcn_mfma_f32_16x16x32_bf16(a1[ktl], wfrag[ktl], acc1, 0, 0, 0);
    }
    // C/D: col=lane&15=c, row=kg*4+j (+16 for second M-tile)
#pragma unroll
    for (int jj = 0; jj < 4; ++jj) {
      pz[kg*4 + jj][c][q]      = acc0[jj];
      pz[16 + kg*4 + jj][c][q] = acc1[jj];
    }
    __syncthreads();

    if (tid < 128) {
      float z[4];
#pragma unroll
      for (int g = 0; g < 4; ++g) {
        const int cc = g*4 + j;
        z[g] = ((pz[b2][cc][0] + pz[b2][cc][1]) + (pz[b2][cc][2] + pz[b2][cc][3]));
      }
      const float zi = z[0] + xv.x, zf = z[1] + xv.y, zc = z[2] + xv.z, zo = z[3] + xv.w;
      const float co = cbuf[b2][j];
      const float cn = sigf(zf)*co + sigf(zi)*tanh_fast(zc);
      const float hn = sigf(zo)*tanh_fast(cn);
      const float hp = hpb[b2][j];
      const bool  mk = t < lenS[b2];
      const float h2 = mk ? hn : hp;
      const float c2 = mk ? cn : co;
      cbuf[b2][j] = c2; hpb[b2][j] = h2;

      const ushort_t hi = bf_hi(h2);
      const ushort_t lo = bf_hi(h2 - bf_f(hi));
      // split-A triplets for the next GEMM: row m=b*800+t, k=d*512+u, K=1024
      {
        size_t ab = 3ULL * ((size_t)(b2*TT + t)*1024 + (d*512 + u));
        Aout[ab] = hi; Aout[ab+1] = lo; Aout[ab+2] = hi;
      }
      // h' fragment-order triplets for step s+1
      {
        ushort_t* hfn = hfrag + (size_t)(d*2 + nxt) * 49152;
        const int r = b2 & 15, mt = b2 >> 4;
#pragma unroll
        for (int jj = 0; jj < 3; ++jj) {
          const int kp = 3*u + jj;
          const int kt = kp >> 5, kg2 = (kp >> 3) & 3, e = kp & 7;
          hfn[((size_t)(mt*48 + kt)*64 + kg2*16 + r)*8 + e] = (jj == 1) ? lo : hi;
        }
      }
      // prefetch next step's xv: latency hides under the grid barrier
      const int s2 = (s + 1 < TT) ? (s + 1) : s;
      const int tn = d ? (TT - 1 - s2) : s2;
      xv = *(const float4*)(xg + (((size_t)d*TT + tn)*BB + b2)*2048 + (size_t)u*4);
    }
    __syncthreads();

    // ---- per-direction grid barrier (two-level monotonic, acq_rel chain) ----
    if (tid == 0) {
      int v = __hip_atomic_fetch_add(gcnt, 1, __ATOMIC_ACQ_REL, __HIP_MEMORY_SCOPE_AGENT) + 1;
      bool rel = false;
      if (v == 16*(s+1)) {
        int r = __hip_atomic_fetch_add(rc, 1, __ATOMIC_ACQ_REL, __HIP_MEMORY_SCOPE_AGENT) + 1;
        if (r == 8*(s+1)) {
          __hip_atomic_store(sense, s+1, __ATOMIC_RELEASE, __HIP_MEMORY_SCOPE_AGENT);
          rel = true;
        }
      }
      if (!rel) {
        while (__hip_atomic_load(sense, __ATOMIC_RELAXED, __HIP_MEMORY_SCOPE_AGENT) < s+1)
          __builtin_amdgcn_s_sleep(1);
      }
      __threadfence();
    }
    __syncthreads();
  }
}

// ---------------- launch ----------------
extern "C" void kernel_launch(void* const* d_in, const int* in_sizes, int n_in,
                              void* d_out, int out_size, void* d_ws, size_t ws_size,
                              hipStream_t stream) {
  const float* x    = (const float*)d_in[0];
  const int*   lens = (const int*)d_in[1];
  const float* Wk1f = (const float*)d_in[2];
  const float* Wr1f = (const float*)d_in[3];
  const float* b1f  = (const float*)d_in[4];
  const float* Wk1b = (const float*)d_in[5];
  const float* Wr1b = (const float*)d_in[6];
  const float* b1b  = (const float*)d_in[7];
  const float* Wk2f = (const float*)d_in[8];
  const float* Wr2f = (const float*)d_in[9];
  const float* b2f  = (const float*)d_in[10];
  const float* Wk2b = (const float*)d_in[11];
  const float* Wr2b = (const float*)d_in[12];
  const float* b2b  = (const float*)d_in[13];
  const float* pW   = (const float*)d_in[14];
  const float* pb   = (const float*)d_in[15];
  float* out = (float*)d_out;

  char* base = (char*)d_ws;
  if (ws_size < WS_TOTAL) {
    void* p = nullptr;
    hipGetSymbolAddress(&p, HIP_SYMBOL(g_ws));
    base = (char*)p;
  }

  ushort_t* Ap  = (ushort_t*)(base + OFF_AP);
  ushort_t* Bt  = (ushort_t*)(base + OFF_BT);
  float*    XG  = (float*)(base + OFF_XG);
  ushort_t* WRP = (ushort_t*)(base + OFF_WRP);
  ushort_t* HF  = (ushort_t*)(base + OFF_HF);
  int*      BARR= (int*)(base + OFF_BARR);

  dim3 tb32x8(32, 8, 1);

  // recurrent-weight split transpose: Wr [512][2048] -> Wr' [2048][1536]
  splitBT<<<dim3(16,64), tb32x8, 0, stream>>>(Wr1f, WRP,              2048, 2048, 1536);
  splitBT<<<dim3(16,64), tb32x8, 0, stream>>>(Wr1b, WRP + 3145728,    2048, 2048, 1536);
  splitBT<<<dim3(16,64), tb32x8, 0, stream>>>(Wr2f, WRP + 2*3145728,  2048, 2048, 1536);
  splitBT<<<dim3(16,64), tb32x8, 0, stream>>>(Wr2b, WRP + 3*3145728,  2048, 2048, 1536);

  // ---- layer 1 ----
  splitA<<<14400, 256, 0, stream>>>(x, Ap, 3686400LL);                       // K=576 -> 1728
  splitBT<<<dim3(18,64), tb32x8, 0, stream>>>(Wk1f, Bt,               2048, 2048, 1728);
  splitBT<<<dim3(18,64), tb32x8, 0, stream>>>(Wk1b, Bt + 2048LL*1728, 2048, 2048, 1728);
  gemm_split<<<dim3(32,200), 256, 0, stream>>>(Ap, Bt, XG, b1f, b1b, 1728, 0);
  hipMemsetAsync(base + OFF_HF, 0, WS_TOTAL - OFF_HF, stream);
  lstm_layer<<<256, 256, 0, stream>>>(XG, WRP, lens, Ap, HF, BARR);          // writes H1 triplets

  // ---- layer 2 ----
  splitBT<<<dim3(32,64), tb32x8, 0, stream>>>(Wk2f, Bt,               2048, 2048, 3072);
  splitBT<<<dim3(32,64), tb32x8, 0, stream>>>(Wk2b, Bt + 2048LL*3072, 2048, 2048, 3072);
  gemm_split<<<dim3(32,200), 256, 0, stream>>>(Ap, Bt, XG, b2f, b2b, 3072, 0);
  hipMemsetAsync(base + OFF_HF, 0, WS_TOTAL - OFF_HF, stream);
  lstm_layer<<<256, 256, 0, stream>>>(XG, WRP + 2*3145728, lens, Ap, HF, BARR); // writes H2 triplets

  // ---- projection ----
  splitBT<<<dim3(32,4), tb32x8, 0, stream>>>(pW, Bt, 80, 80, 3072);          // pad N to 128
  gemm_split<<<dim3(1,200), 256, 0, stream>>>(Ap, Bt, out, pb, nullptr, 3072, 1);
}

// Round 5
// 30896.182 us; speedup vs baseline: 1.5195x; 1.1230x over previous
//
#include <hip/hip_runtime.h>
#include <hip/hip_bf16.h>

#define TT 800
#define BB 32

typedef unsigned short ushort_t;
using bf16x8 = __attribute__((ext_vector_type(8))) short;
using f32x4  = __attribute__((ext_vector_type(4))) float;

// ---------------- workspace layout ----------------
#define OFF_AP   0ULL                  // 25600*3072*2   = 157286400
#define OFF_BT   157286400ULL          // 4096*3072*2    =  25165824
#define OFF_XG   182452224ULL          // 2*800*32*2048*4= 419430400
#define OFF_WRP  601882624ULL          // 4*2048*1536*2  =  25165824
#define OFF_HF   627048448ULL          // 4*49152*2      =    393216
#define OFF_BARR 627441664ULL          // 32768 (flags 256*64B + sense)
#define WS_TOTAL 627474432ULL

// Static fallback workspace: allocated at module load => graph-capture safe.
__device__ char g_ws[WS_TOTAL];

// ---------------- helpers ----------------
__device__ __forceinline__ ushort_t bf_hi(float v) {
  __hip_bfloat16 h = __float2bfloat16(v);
  return __builtin_bit_cast(ushort_t, h);
}
__device__ __forceinline__ float bf_f(ushort_t u) {
  __hip_bfloat16 h = __builtin_bit_cast(__hip_bfloat16, u);
  return __bfloat162float(h);
}
__device__ __forceinline__ float sigf(float x)      { return 1.0f / (1.0f + __expf(-x)); }
__device__ __forceinline__ float tanh_fast(float x) { return 2.0f / (1.0f + __expf(-2.0f*x)) - 1.0f; }

__device__ __forceinline__ void gload16(const void* g, void* l) {
  __builtin_amdgcn_global_load_lds((const __attribute__((address_space(1))) void*)g,
                                   (__attribute__((address_space(3))) void*)l,
                                   16, 0, 0);
}

// ---------------- fp32 -> (hi,lo,hi) bf16 K-interleave for A ----------------
__global__ __launch_bounds__(256) void splitA(const float* __restrict__ src,
                                              ushort_t* __restrict__ dst,
                                              long long total) {
  long long idx = (long long)blockIdx.x * 256 + threadIdx.x;
  if (idx >= total) return;
  float4 v = ((const float4*)src)[idx];
  float vs[4] = {v.x, v.y, v.z, v.w};
  ushort_t o[12];
#pragma unroll
  for (int e = 0; e < 4; ++e) {
    ushort_t hi = bf_hi(vs[e]);
    ushort_t lo = bf_hi(vs[e] - bf_f(hi));
    o[3*e] = hi; o[3*e+1] = lo; o[3*e+2] = hi;
  }
  ushort4* dp = (ushort4*)(dst + 12*idx);
  dp[0] = make_ushort4(o[0], o[1], o[2], o[3]);
  dp[1] = make_ushort4(o[4], o[5], o[6], o[7]);
  dp[2] = make_ushort4(o[8], o[9], o[10], o[11]);
}

// ---------------- fp32 [K][N] -> bf16 [n][3K] transposed split for B ----------------
__global__ __launch_bounds__(256) void splitBT(const float* __restrict__ src,
                                               ushort_t* __restrict__ dst,
                                               int srcPitch, int Nvalid, int dstPitch) {
  __shared__ float tile[32][33];
  int k0 = blockIdx.x * 32, n0 = blockIdx.y * 32;
  int tx = threadIdx.x, ty = threadIdx.y;   // (32,8)
#pragma unroll
  for (int i = 0; i < 4; ++i) {
    int k = k0 + ty + i*8;
    int n = n0 + tx;
    float v = 0.f;
    if (n < Nvalid) v = src[(long long)k * srcPitch + n];
    tile[ty + i*8][tx] = v;
  }
  __syncthreads();
#pragma unroll
  for (int q = 0; q < 4; ++q) {
    int kk = ty*4 + q;
    float v = tile[kk][tx];
    ushort_t hi = bf_hi(v);
    ushort_t lo = bf_hi(v - bf_f(hi));
    long long off = (long long)(n0 + tx) * dstPitch + 3*(k0 + kk);
    dst[off] = hi; dst[off+1] = hi; dst[off+2] = lo;
  }
}

// ---------------- split-bf16 GEMM (m97-style, 128x128 tile, BK=32) ----------------
__global__ __launch_bounds__(256) void gemm_split(
    const ushort_t* __restrict__ A, const ushort_t* __restrict__ Bt,
    float* __restrict__ out, const float* __restrict__ bias0,
    const float* __restrict__ bias1, int Kp, int mode)
{
  __shared__ ushort_t As[128*32];
  __shared__ ushort_t Bs[128*32];
  const int tid  = threadIdx.x;
  const int lane = tid & 63, wid = tid >> 6;
  const int m0 = blockIdx.y * 128, n0 = blockIdx.x * 128;
  const int wm = (wid >> 1) * 64, wn = (wid & 1) * 64;
  const int frow = lane & 15, fkg = (lane >> 4) * 8;

  f32x4 acc[4][4] = {};

  for (int k0 = 0; k0 < Kp; k0 += 32) {
#pragma unroll
    for (int i = 0; i < 2; ++i) {
      int c = tid + i*256;
      int r = c >> 2, co = (c & 3) * 8;
      gload16(A  + (size_t)(m0 + r) * Kp + k0 + co, (void*)(As + c*8));
      gload16(Bt + (size_t)(n0 + r) * Kp + k0 + co, (void*)(Bs + c*8));
    }
    __syncthreads();
    bf16x8 af[4], bq[4];
#pragma unroll
    for (int f = 0; f < 4; ++f) {
      af[f] = *(const bf16x8*)(As + (wm + f*16 + frow)*32 + fkg);
      bq[f] = *(const bf16x8*)(Bs + (wn + f*16 + frow)*32 + fkg);
    }
#pragma unroll
    for (int mf = 0; mf < 4; ++mf)
#pragma unroll
      for (int nf = 0; nf < 4; ++nf)
        acc[mf][nf] = __builtin_amdgcn_mfma_f32_16x16x32_bf16(af[mf], bq[nf], acc[mf][nf], 0, 0, 0);
    __syncthreads();
  }

  const int r4 = (lane >> 4) * 4, ccol = lane & 15;
#pragma unroll
  for (int mf = 0; mf < 4; ++mf)
#pragma unroll
    for (int nf = 0; nf < 4; ++nf) {
#pragma unroll
      for (int j = 0; j < 4; ++j) {
        int m = m0 + wm + mf*16 + r4 + j;
        int n = n0 + wn + nf*16 + ccol;
        float v = acc[mf][nf][j];
        int t = m % TT, b = m / TT;
        if (mode == 0) {
          int d2 = n >> 11, n2 = n & 2047, g = n2 >> 9, u2 = n2 & 511;
          v += (d2 == 0 ? bias0[n2] : bias1[n2]);
          out[(((size_t)d2*TT + t)*BB + b)*2048 + u2*4 + g] = v;
        } else {
          if (n < 80) out[(size_t)m*80 + n] = v + bias0[n];
        }
      }
    }
}

// ---------------- persistent bidirectional LSTM layer (MFMA recurrence) ----------------
// 256 WGs x 256 thr, 1 WG/CU. WG w: dir d=w>>7, unit-block u0=(w&127)*4.
// Per step: each wave issues 24 global_load_lds (h' fragments, zero VGPR cost,
// full memory-level parallelism), one vmcnt(0), then ds_read+MFMA.
// Grid barrier: per-WG release-store flag (64B stride, no RMW contention);
// master wave per direction polls 128 flags via 64-lane loads; sense broadcast.
__global__ __launch_bounds__(256, 2) void lstm_layer(
    const float* __restrict__ xg, const ushort_t* __restrict__ wrp,
    const int* __restrict__ lens, ushort_t* __restrict__ Aout,
    ushort_t* __restrict__ hfrag, int* __restrict__ barr)
{
  const int w   = blockIdx.x;
  const int d   = w >> 7;
  const int u0  = (w & 127) * 4;
  const int tid = threadIdx.x;
  const int q    = tid >> 6;         // wave = K'-quarter
  const int lane = tid & 63;
  const int c    = lane & 15;        // local col 0..15 (g=c>>2, j=c&3)
  const int kg   = lane >> 4;        // k-subgroup 0..3
  const int gc   = (c >> 2) * 512 + u0 + (c & 3);

  __shared__ ushort_t stage[4][24][512]; // 98304B: [wave][ktile(M0:0-11,M1:12-23)][lane*8]
  __shared__ float pz[32][16][5];        // [b][c][kq-partial] (+1 pad)
  __shared__ float cbuf[32][4];
  __shared__ float hpb[32][4];
  __shared__ int   lenS[32];

  if (tid < 32)  lenS[tid] = lens[tid];
  if (tid < 128) { cbuf[tid >> 2][tid & 3] = 0.f; hpb[tid >> 2][tid & 3] = 0.f; }

  // ---- load weight B-fragments once: wave q holds K'-range [384q, 384q+384) ----
  bf16x8 wfrag[12];
  {
    const ushort_t* wr = wrp + (size_t)d * 2048 * 1536 + (size_t)gc * 1536;
#pragma unroll
    for (int ktl = 0; ktl < 12; ++ktl)
      wfrag[ktl] = *(const bf16x8*)(wr + (12*q + ktl)*32 + kg*8);
  }
  __syncthreads();

  // barrier region: flags[w] @ barr[w*16] (64B stride); sense[d] @ barr[4096+d*16]
  int* myflag = barr + w*16;
  int* sense  = barr + 4096 + d*16;
  const bool isMaster = (w & 127) == 0;
  int* pf0 = barr + (d*128 + lane)*16;        // master wave: 2 flags per lane
  int* pf1 = barr + (d*128 + 64 + lane)*16;

  // gate-phase thread mapping (tid<128): b2, j, global unit u
  const int b2 = tid >> 2, j = tid & 3;
  const int u  = u0 + j;
  // prefetch xv for step 0
  float4 xv = {0.f,0.f,0.f,0.f};
  if (tid < 128) {
    const int t0 = d ? (TT-1) : 0;
    xv = *(const float4*)(xg + (((size_t)d*TT + t0)*BB + b2)*2048 + (size_t)u*4);
  }

  for (int s = 0; s < TT; ++s) {
    const int t = d ? (TT - 1 - s) : s;
    const int cur = s & 1, nxt = cur ^ 1;

    // ---- stage h' fragments into LDS (24 async direct-to-LDS loads, no VGPRs) ----
    const ushort_t* hf  = hfrag + (size_t)(d*2 + cur) * 49152;
    const ushort_t* p0  = hf + ((size_t)(12*q)*64 + lane)*8;
#pragma unroll
    for (int ktl = 0; ktl < 12; ++ktl) {
      gload16(p0 + ktl*512,         &stage[q][ktl][lane*8]);      // M-tile 0
      gload16(p0 + 24576 + ktl*512, &stage[q][12 + ktl][lane*8]); // M-tile 1
    }
    asm volatile("s_waitcnt vmcnt(0)" ::: "memory");
    __builtin_amdgcn_sched_barrier(0);

    f32x4 acc0 = {0.f,0.f,0.f,0.f}, acc1 = {0.f,0.f,0.f,0.f};
#pragma unroll
    for (int ktl = 0; ktl < 12; ++ktl) {
      bf16x8 a0 = *(const bf16x8*)&stage[q][ktl][lane*8];
      bf16x8 a1 = *(const bf16x8*)&stage[q][12 + ktl][lane*8];
      acc0 = __builtin_amdgcn_mfma_f32_16x16x32_bf16(a0, wfrag[ktl], acc0, 0, 0, 0);
      acc1 = __builtin_amdgcn_mfma_f32_16x16x32_bf16(a1, wfrag[ktl], acc1, 0, 0, 0);
    }
    // C/D: col=lane&15=c, row=kg*4+j (+16 for second M-tile)
#pragma unroll
    for (int jj = 0; jj < 4; ++jj) {
      pz[kg*4 + jj][c][q]      = acc0[jj];
      pz[16 + kg*4 + jj][c][q] = acc1[jj];
    }
    __syncthreads();

    if (tid < 128) {
      float z[4];
#pragma unroll
      for (int g = 0; g < 4; ++g) {
        const int cc = g*4 + j;
        z[g] = ((pz[b2][cc][0] + pz[b2][cc][1]) + (pz[b2][cc][2] + pz[b2][cc][3]));
      }
      const float zi = z[0] + xv.x, zf = z[1] + xv.y, zc = z[2] + xv.z, zo = z[3] + xv.w;
      const float co = cbuf[b2][j];
      const float cn = sigf(zf)*co + sigf(zi)*tanh_fast(zc);
      const float hn = sigf(zo)*tanh_fast(cn);
      const float hp = hpb[b2][j];
      const bool  mk = t < lenS[b2];
      const float h2 = mk ? hn : hp;
      const float c2 = mk ? cn : co;
      cbuf[b2][j] = c2; hpb[b2][j] = h2;

      const ushort_t hi = bf_hi(h2);
      const ushort_t lo = bf_hi(h2 - bf_f(hi));
      // split-A triplets for the next GEMM: row m=b*800+t, k=d*512+u, K=1024
      {
        size_t ab = 3ULL * ((size_t)(b2*TT + t)*1024 + (d*512 + u));
        Aout[ab] = hi; Aout[ab+1] = lo; Aout[ab+2] = hi;
      }
      // h' fragment-order triplets for step s+1
      {
        ushort_t* hfn = hfrag + (size_t)(d*2 + nxt) * 49152;
        const int r = b2 & 15, mt = b2 >> 4;
#pragma unroll
        for (int jj = 0; jj < 3; ++jj) {
          const int kp = 3*u + jj;
          const int kt = kp >> 5, kg2 = (kp >> 3) & 3, e = kp & 7;
          hfn[((size_t)(mt*48 + kt)*64 + kg2*16 + r)*8 + e] = (jj == 1) ? lo : hi;
        }
      }
      // prefetch next step's xv: latency hides under the grid barrier
      const int s2 = (s + 1 < TT) ? (s + 1) : s;
      const int tn = d ? (TT - 1 - s2) : s2;
      xv = *(const float4*)(xg + (((size_t)d*TT + tn)*BB + b2)*2048 + (size_t)u*4);
    }
    __syncthreads();   // drains vmcnt/lgkmcnt: all h' stores issued & complete

    // ---- grid barrier: flag stores + master poll + sense broadcast ----
    if (isMaster) {
      if (q == 0) {   // master wave (tid 0..63) polls all 128 flags of its direction
        if (tid == 0)
          __hip_atomic_store(myflag, s+1, __ATOMIC_RELEASE, __HIP_MEMORY_SCOPE_AGENT);
        for (;;) {
          int f0 = __hip_atomic_load(pf0, __ATOMIC_RELAXED, __HIP_MEMORY_SCOPE_AGENT);
          int f1 = __hip_atomic_load(pf1, __ATOMIC_RELAXED, __HIP_MEMORY_SCOPE_AGENT);
          if (__all(f0 >= s+1 && f1 >= s+1)) break;
          __builtin_amdgcn_s_sleep(1);
        }
        __threadfence();
        if (tid == 0)
          __hip_atomic_store(sense, s+1, __ATOMIC_RELEASE, __HIP_MEMORY_SCOPE_AGENT);
      }
    } else if (tid == 0) {
      __hip_atomic_store(myflag, s+1, __ATOMIC_RELEASE, __HIP_MEMORY_SCOPE_AGENT);
      while (__hip_atomic_load(sense, __ATOMIC_RELAXED, __HIP_MEMORY_SCOPE_AGENT) < s+1)
        __builtin_amdgcn_s_sleep(1);
      __threadfence();
    }
    __syncthreads();
  }
}

// ---------------- launch ----------------
extern "C" void kernel_launch(void* const* d_in, const int* in_sizes, int n_in,
                              void* d_out, int out_size, void* d_ws, size_t ws_size,
                              hipStream_t stream) {
  const float* x    = (const float*)d_in[0];
  const int*   lens = (const int*)d_in[1];
  const float* Wk1f = (const float*)d_in[2];
  const float* Wr1f = (const float*)d_in[3];
  const float* b1f  = (const float*)d_in[4];
  const float* Wk1b = (const float*)d_in[5];
  const float* Wr1b = (const float*)d_in[6];
  const float* b1b  = (const float*)d_in[7];
  const float* Wk2f = (const float*)d_in[8];
  const float* Wr2f = (const float*)d_in[9];
  const float* b2f  = (const float*)d_in[10];
  const float* Wk2b = (const float*)d_in[11];
  const float* Wr2b = (const float*)d_in[12];
  const float* b2b  = (const float*)d_in[13];
  const float* pW   = (const float*)d_in[14];
  const float* pb   = (const float*)d_in[15];
  float* out = (float*)d_out;

  char* base = (char*)d_ws;
  if (ws_size < WS_TOTAL) {
    void* p = nullptr;
    hipGetSymbolAddress(&p, HIP_SYMBOL(g_ws));
    base = (char*)p;
  }

  ushort_t* Ap  = (ushort_t*)(base + OFF_AP);
  ushort_t* Bt  = (ushort_t*)(base + OFF_BT);
  float*    XG  = (float*)(base + OFF_XG);
  ushort_t* WRP = (ushort_t*)(base + OFF_WRP);
  ushort_t* HF  = (ushort_t*)(base + OFF_HF);
  int*      BARR= (int*)(base + OFF_BARR);

  dim3 tb32x8(32, 8, 1);

  // recurrent-weight split transpose: Wr [512][2048] -> Wr' [2048][1536]
  splitBT<<<dim3(16,64), tb32x8, 0, stream>>>(Wr1f, WRP,              2048, 2048, 1536);
  splitBT<<<dim3(16,64), tb32x8, 0, stream>>>(Wr1b, WRP + 3145728,    2048, 2048, 1536);
  splitBT<<<dim3(16,64), tb32x8, 0, stream>>>(Wr2f, WRP + 2*3145728,  2048, 2048, 1536);
  splitBT<<<dim3(16,64), tb32x8, 0, stream>>>(Wr2b, WRP + 3*3145728,  2048, 2048, 1536);

  // ---- layer 1 ----
  splitA<<<14400, 256, 0, stream>>>(x, Ap, 3686400LL);                       // K=576 -> 1728
  splitBT<<<dim3(18,64), tb32x8, 0, stream>>>(Wk1f, Bt,               2048, 2048, 1728);
  splitBT<<<dim3(18,64), tb32x8, 0, stream>>>(Wk1b, Bt + 2048LL*1728, 2048, 2048, 1728);
  gemm_split<<<dim3(32,200), 256, 0, stream>>>(Ap, Bt, XG, b1f, b1b, 1728, 0);
  hipMemsetAsync(base + OFF_HF, 0, WS_TOTAL - OFF_HF, stream);
  lstm_layer<<<256, 256, 0, stream>>>(XG, WRP, lens, Ap, HF, BARR);          // writes H1 triplets

  // ---- layer 2 ----
  splitBT<<<dim3(32,64), tb32x8, 0, stream>>>(Wk2f, Bt,               2048, 2048, 3072);
  splitBT<<<dim3(32,64), tb32x8, 0, stream>>>(Wk2b, Bt + 2048LL*3072, 2048, 2048, 3072);
  gemm_split<<<dim3(32,200), 256, 0, stream>>>(Ap, Bt, XG, b2f, b2b, 3072, 0);
  hipMemsetAsync(base + OFF_HF, 0, WS_TOTAL - OFF_HF, stream);
  lstm_layer<<<256, 256, 0, stream>>>(XG, WRP + 2*3145728, lens, Ap, HF, BARR); // writes H2 triplets

  // ---- projection ----
  splitBT<<<dim3(32,4), tb32x8, 0, stream>>>(pW, Bt, 80, 80, 3072);          // pad N to 128
  gemm_split<<<dim3(1,200), 256, 0, stream>>>(Ap, Bt, out, pb, nullptr, 3072, 1);
}

// Round 8
// 10306.676 us; speedup vs baseline: 4.5551x; 2.9977x over previous
//
#include <hip/hip_runtime.h>
#include <hip/hip_bf16.h>

#define TT 800
#define BB 32

typedef unsigned short ushort_t;
using bf16x8 = __attribute__((ext_vector_type(8))) short;
using f32x4  = __attribute__((ext_vector_type(4))) float;

// ---------------- workspace layout ----------------
#define OFF_AP   0ULL                  // 25600*3072*2   = 157286400
#define OFF_BT   157286400ULL          // 4096*3072*2    =  25165824
#define OFF_XG   182452224ULL          // 2*800*32*2048*4= 419430400
#define OFF_WRP  601882624ULL          // 4*2048*1536*2  =  25165824
#define OFF_HF   627048448ULL          // 4*49152*2      =    393216
#define OFF_BARR 627441664ULL          // 32768 (flags 256*64B + sense)
#define WS_TOTAL 627474432ULL

// Static fallback workspace: allocated at module load => graph-capture safe.
__device__ char g_ws[WS_TOTAL];

// ---------------- helpers ----------------
__device__ __forceinline__ ushort_t bf_hi(float v) {
  __hip_bfloat16 h = __float2bfloat16(v);
  return __builtin_bit_cast(ushort_t, h);
}
__device__ __forceinline__ float bf_f(ushort_t u) {
  __hip_bfloat16 h = __builtin_bit_cast(__hip_bfloat16, u);
  return __bfloat162float(h);
}
__device__ __forceinline__ float sigf(float x)      { return 1.0f / (1.0f + __expf(-x)); }
__device__ __forceinline__ float tanh_fast(float x) { return 2.0f / (1.0f + __expf(-2.0f*x)) - 1.0f; }

__device__ __forceinline__ void gload16(const void* g, void* l) {
  __builtin_amdgcn_global_load_lds((const __attribute__((address_space(1))) void*)g,
                                   (__attribute__((address_space(3))) void*)l,
                                   16, 0, 0);
}
// system-coherent direct-to-LDS load: SC0|SC1 = 0x11 -> bypass L1/L2, read L3
__device__ __forceinline__ void gload16_sys(const void* g, void* l) {
  __builtin_amdgcn_global_load_lds((const __attribute__((address_space(1))) void*)g,
                                   (__attribute__((address_space(3))) void*)l,
                                   16, 0, 17);
}
// system-coherent 2B store: write-through past L2 to L3 (no wbl2 needed)
__device__ __forceinline__ void store_short_sys(ushort_t* p, ushort_t v) {
  unsigned int vv = v;
  asm volatile("global_store_short %0, %1, off sc0 sc1" :: "v"(p), "v"(vv) : "memory");
}

// ---------------- fp32 -> (hi,lo,hi) bf16 K-interleave for A ----------------
__global__ __launch_bounds__(256) void splitA(const float* __restrict__ src,
                                              ushort_t* __restrict__ dst,
                                              long long total) {
  long long idx = (long long)blockIdx.x * 256 + threadIdx.x;
  if (idx >= total) return;
  float4 v = ((const float4*)src)[idx];
  float vs[4] = {v.x, v.y, v.z, v.w};
  ushort_t o[12];
#pragma unroll
  for (int e = 0; e < 4; ++e) {
    ushort_t hi = bf_hi(vs[e]);
    ushort_t lo = bf_hi(vs[e] - bf_f(hi));
    o[3*e] = hi; o[3*e+1] = lo; o[3*e+2] = hi;
  }
  ushort4* dp = (ushort4*)(dst + 12*idx);
  dp[0] = make_ushort4(o[0], o[1], o[2], o[3]);
  dp[1] = make_ushort4(o[4], o[5], o[6], o[7]);
  dp[2] = make_ushort4(o[8], o[9], o[10], o[11]);
}

// ---------------- fp32 [K][N] -> bf16 [n][3K] transposed split for B ----------------
__global__ __launch_bounds__(256) void splitBT(const float* __restrict__ src,
                                               ushort_t* __restrict__ dst,
                                               int srcPitch, int Nvalid, int dstPitch) {
  __shared__ float tile[32][33];
  int k0 = blockIdx.x * 32, n0 = blockIdx.y * 32;
  int tx = threadIdx.x, ty = threadIdx.y;   // (32,8)
#pragma unroll
  for (int i = 0; i < 4; ++i) {
    int k = k0 + ty + i*8;
    int n = n0 + tx;
    float v = 0.f;
    if (n < Nvalid) v = src[(long long)k * srcPitch + n];
    tile[ty + i*8][tx] = v;
  }
  __syncthreads();
#pragma unroll
  for (int q = 0; q < 4; ++q) {
    int kk = ty*4 + q;
    float v = tile[kk][tx];
    ushort_t hi = bf_hi(v);
    ushort_t lo = bf_hi(v - bf_f(hi));
    long long off = (long long)(n0 + tx) * dstPitch + 3*(k0 + kk);
    dst[off] = hi; dst[off+1] = hi; dst[off+2] = lo;
  }
}

// ---------------- split-bf16 GEMM (m97-style, 128x128 tile, BK=32) ----------------
__global__ __launch_bounds__(256) void gemm_split(
    const ushort_t* __restrict__ A, const ushort_t* __restrict__ Bt,
    float* __restrict__ out, const float* __restrict__ bias0,
    const float* __restrict__ bias1, int Kp, int mode)
{
  __shared__ ushort_t As[128*32];
  __shared__ ushort_t Bs[128*32];
  const int tid  = threadIdx.x;
  const int lane = tid & 63, wid = tid >> 6;
  const int m0 = blockIdx.y * 128, n0 = blockIdx.x * 128;
  const int wm = (wid >> 1) * 64, wn = (wid & 1) * 64;
  const int frow = lane & 15, fkg = (lane >> 4) * 8;

  f32x4 acc[4][4] = {};

  for (int k0 = 0; k0 < Kp; k0 += 32) {
#pragma unroll
    for (int i = 0; i < 2; ++i) {
      int c = tid + i*256;
      int r = c >> 2, co = (c & 3) * 8;
      gload16(A  + (size_t)(m0 + r) * Kp + k0 + co, (void*)(As + c*8));
      gload16(Bt + (size_t)(n0 + r) * Kp + k0 + co, (void*)(Bs + c*8));
    }
    __syncthreads();
    bf16x8 af[4], bq[4];
#pragma unroll
    for (int f = 0; f < 4; ++f) {
      af[f] = *(const bf16x8*)(As + (wm + f*16 + frow)*32 + fkg);
      bq[f] = *(const bf16x8*)(Bs + (wn + f*16 + frow)*32 + fkg);
    }
#pragma unroll
    for (int mf = 0; mf < 4; ++mf)
#pragma unroll
      for (int nf = 0; nf < 4; ++nf)
        acc[mf][nf] = __builtin_amdgcn_mfma_f32_16x16x32_bf16(af[mf], bq[nf], acc[mf][nf], 0, 0, 0);
    __syncthreads();
  }

  const int r4 = (lane >> 4) * 4, ccol = lane & 15;
#pragma unroll
  for (int mf = 0; mf < 4; ++mf)
#pragma unroll
    for (int nf = 0; nf < 4; ++nf) {
#pragma unroll
      for (int j = 0; j < 4; ++j) {
        int m = m0 + wm + mf*16 + r4 + j;
        int n = n0 + wn + nf*16 + ccol;
        float v = acc[mf][nf][j];
        int t = m % TT, b = m / TT;
        if (mode == 0) {
          int d2 = n >> 11, n2 = n & 2047, g = n2 >> 9, u2 = n2 & 511;
          v += (d2 == 0 ? bias0[n2] : bias1[n2]);
          out[(((size_t)d2*TT + t)*BB + b)*2048 + u2*4 + g] = v;
        } else {
          if (n < 80) out[(size_t)m*80 + n] = v + bias0[n];
        }
      }
    }
}

// ---------------- persistent bidirectional LSTM layer (MFMA recurrence) ----------------
// 256 WGs x 256 thr, 1 WG/CU. WG w: dir d=w>>7, unit-block u0=(w&127)*4.
// Cross-WG exchange entirely via memory-side L3: h' stores are sc0sc1
// write-through shorts, h' loads are sc0sc1 global_load_lds, barrier flags are
// RELAXED system-scope atomics. NO release fences / threadfence on the fast
// path (the per-step buffer_wbl2/buffer_inv L2 maintenance was the 10+us/step
// cost in R3-R5). Ordering: vmcnt(0) drain before the barrier puts all
// write-through h' stores at L3 before the flag store after __syncthreads().
// Anti-hang insurance: if a spin exceeds SPIN_LIMIT iters, issue one
// __threadfence() (L2 inv) and keep polling -> degrades to R5 behavior
// instead of hanging if the sc0sc1-bypass model is wrong on this HW.
#define SPIN_LIMIT 16384
__global__ __launch_bounds__(256, 2) void lstm_layer(
    const float* __restrict__ xg, const ushort_t* __restrict__ wrp,
    const int* __restrict__ lens, ushort_t* __restrict__ Aout,
    ushort_t* __restrict__ hfrag, int* __restrict__ barr)
{
  const int w   = blockIdx.x;
  const int d   = w >> 7;
  const int u0  = (w & 127) * 4;
  const int tid = threadIdx.x;
  const int q    = tid >> 6;         // wave = K'-quarter
  const int lane = tid & 63;
  const int c    = lane & 15;        // local col 0..15 (g=c>>2, j=c&3)
  const int kg   = lane >> 4;        // k-subgroup 0..3
  const int gc   = (c >> 2) * 512 + u0 + (c & 3);

  __shared__ ushort_t stage[4][24][512]; // 98304B: [wave][ktile(M0:0-11,M1:12-23)][lane*8]
  __shared__ float pz[32][16][5];        // [b][c][kq-partial] (+1 pad)
  __shared__ float cbuf[32][4];
  __shared__ float hpb[32][4];
  __shared__ int   lenS[32];

  if (tid < 32)  lenS[tid] = lens[tid];
  if (tid < 128) { cbuf[tid >> 2][tid & 3] = 0.f; hpb[tid >> 2][tid & 3] = 0.f; }

  // ---- load weight B-fragments once: wave q holds K'-range [384q, 384q+384) ----
  bf16x8 wfrag[12];
  {
    const ushort_t* wr = wrp + (size_t)d * 2048 * 1536 + (size_t)gc * 1536;
#pragma unroll
    for (int ktl = 0; ktl < 12; ++ktl)
      wfrag[ktl] = *(const bf16x8*)(wr + (12*q + ktl)*32 + kg*8);
  }
  __syncthreads();

  // barrier region: flags[w] @ barr[w*16] (64B stride); sense[d] @ barr[4096+d*16]
  int* myflag = barr + w*16;
  int* sense  = barr + 4096 + d*16;
  const bool isMaster = (w & 127) == 0;
  int* pf0 = barr + (d*128 + lane)*16;        // master wave: 2 flags per lane
  int* pf1 = barr + (d*128 + 64 + lane)*16;

  // gate-phase thread mapping (tid<128): b2, j, global unit u
  const int b2 = tid >> 2, j = tid & 3;
  const int u  = u0 + j;
  // prefetch xv for step 0
  float4 xv = {0.f,0.f,0.f,0.f};
  if (tid < 128) {
    const int t0 = d ? (TT-1) : 0;
    xv = *(const float4*)(xg + (((size_t)d*TT + t0)*BB + b2)*2048 + (size_t)u*4);
  }

  for (int s = 0; s < TT; ++s) {
    const int t = d ? (TT - 1 - s) : s;
    const int cur = s & 1, nxt = cur ^ 1;

    // ---- stage h' fragments into LDS (24 async system-coherent loads, no VGPRs) ----
    const ushort_t* hf  = hfrag + (size_t)(d*2 + cur) * 49152;
    const ushort_t* p0  = hf + ((size_t)(12*q)*64 + lane)*8;
#pragma unroll
    for (int ktl = 0; ktl < 12; ++ktl) {
      gload16_sys(p0 + ktl*512,         &stage[q][ktl][lane*8]);      // M-tile 0
      gload16_sys(p0 + 24576 + ktl*512, &stage[q][12 + ktl][lane*8]); // M-tile 1
    }
    asm volatile("s_waitcnt vmcnt(0)" ::: "memory");
    __builtin_amdgcn_sched_barrier(0);

    f32x4 acc0 = {0.f,0.f,0.f,0.f}, acc1 = {0.f,0.f,0.f,0.f};
#pragma unroll
    for (int ktl = 0; ktl < 12; ++ktl) {
      bf16x8 a0 = *(const bf16x8*)&stage[q][ktl][lane*8];
      bf16x8 a1 = *(const bf16x8*)&stage[q][12 + ktl][lane*8];
      acc0 = __builtin_amdgcn_mfma_f32_16x16x32_bf16(a0, wfrag[ktl], acc0, 0, 0, 0);
      acc1 = __builtin_amdgcn_mfma_f32_16x16x32_bf16(a1, wfrag[ktl], acc1, 0, 0, 0);
    }
    // C/D: col=lane&15=c, row=kg*4+j (+16 for second M-tile)
#pragma unroll
    for (int jj = 0; jj < 4; ++jj) {
      pz[kg*4 + jj][c][q]      = acc0[jj];
      pz[16 + kg*4 + jj][c][q] = acc1[jj];
    }
    __syncthreads();

    if (tid < 128) {
      float z[4];
#pragma unroll
      for (int g = 0; g < 4; ++g) {
        const int cc = g*4 + j;
        z[g] = ((pz[b2][cc][0] + pz[b2][cc][1]) + (pz[b2][cc][2] + pz[b2][cc][3]));
      }
      const float zi = z[0] + xv.x, zf = z[1] + xv.y, zc = z[2] + xv.z, zo = z[3] + xv.w;
      const float co = cbuf[b2][j];
      const float cn = sigf(zf)*co + sigf(zi)*tanh_fast(zc);
      const float hn = sigf(zo)*tanh_fast(cn);
      const float hp = hpb[b2][j];
      const bool  mk = t < lenS[b2];
      const float h2 = mk ? hn : hp;
      const float c2 = mk ? cn : co;
      cbuf[b2][j] = c2; hpb[b2][j] = h2;

      const ushort_t hi = bf_hi(h2);
      const ushort_t lo = bf_hi(h2 - bf_f(hi));
      // split-A triplets for the next GEMM (plain cached stores; flushed at kernel end)
      {
        size_t ab = 3ULL * ((size_t)(b2*TT + t)*1024 + (d*512 + u));
        Aout[ab] = hi; Aout[ab+1] = lo; Aout[ab+2] = hi;
      }
      // h' fragment-order triplets for step s+1 (write-through to L3)
      {
        ushort_t* hfn = hfrag + (size_t)(d*2 + nxt) * 49152;
        const int r = b2 & 15, mt = b2 >> 4;
#pragma unroll
        for (int jj = 0; jj < 3; ++jj) {
          const int kp = 3*u + jj;
          const int kt = kp >> 5, kg2 = (kp >> 3) & 3, e = kp & 7;
          store_short_sys(&hfn[((size_t)(mt*48 + kt)*64 + kg2*16 + r)*8 + e],
                          (jj == 1) ? lo : hi);
        }
      }
      // prefetch next step's xv: latency hides under the grid barrier
      const int s2 = (s + 1 < TT) ? (s + 1) : s;
      const int tn = d ? (TT - 1 - s2) : s2;
      xv = *(const float4*)(xg + (((size_t)d*TT + tn)*BB + b2)*2048 + (size_t)u*4);
    }
    // drain write-through h' stores to L3 before the barrier/flags
    asm volatile("s_waitcnt vmcnt(0)" ::: "memory");
    __syncthreads();

    // ---- grid barrier: relaxed system-scope flags, no fast-path fences ----
    if (isMaster) {
      if (q == 0) {   // master wave polls all 128 flags of its direction
        if (tid == 0)
          __hip_atomic_store(myflag, s+1, __ATOMIC_RELAXED, __HIP_MEMORY_SCOPE_SYSTEM);
        int spin = 0;
        for (;;) {
          int f0 = __hip_atomic_load(pf0, __ATOMIC_RELAXED, __HIP_MEMORY_SCOPE_SYSTEM);
          int f1 = __hip_atomic_load(pf1, __ATOMIC_RELAXED, __HIP_MEMORY_SCOPE_SYSTEM);
          if (__all(f0 >= s+1 && f1 >= s+1)) break;
          __builtin_amdgcn_s_sleep(1);
          if (++spin >= SPIN_LIMIT) { spin = 0; __threadfence(); }  // anti-hang fallback
        }
        if (tid == 0)
          __hip_atomic_store(sense, s+1, __ATOMIC_RELAXED, __HIP_MEMORY_SCOPE_SYSTEM);
      }
    } else if (tid == 0) {
      __hip_atomic_store(myflag, s+1, __ATOMIC_RELAXED, __HIP_MEMORY_SCOPE_SYSTEM);
      int spin = 0;
      while (__hip_atomic_load(sense, __ATOMIC_RELAXED, __HIP_MEMORY_SCOPE_SYSTEM) < s+1) {
        __builtin_amdgcn_s_sleep(1);
        if (++spin >= SPIN_LIMIT) { spin = 0; __threadfence(); }    // anti-hang fallback
      }
    }
    __syncthreads();
  }
}

// ---------------- launch ----------------
extern "C" void kernel_launch(void* const* d_in, const int* in_sizes, int n_in,
                              void* d_out, int out_size, void* d_ws, size_t ws_size,
                              hipStream_t stream) {
  const float* x    = (const float*)d_in[0];
  const int*   lens = (const int*)d_in[1];
  const float* Wk1f = (const float*)d_in[2];
  const float* Wr1f = (const float*)d_in[3];
  const float* b1f  = (const float*)d_in[4];
  const float* Wk1b = (const float*)d_in[5];
  const float* Wr1b = (const float*)d_in[6];
  const float* b1b  = (const float*)d_in[7];
  const float* Wk2f = (const float*)d_in[8];
  const float* Wr2f = (const float*)d_in[9];
  const float* b2f  = (const float*)d_in[10];
  const float* Wk2b = (const float*)d_in[11];
  const float* Wr2b = (const float*)d_in[12];
  const float* b2b  = (const float*)d_in[13];
  const float* pW   = (const float*)d_in[14];
  const float* pb   = (const float*)d_in[15];
  float* out = (float*)d_out;

  char* base = (char*)d_ws;
  if (ws_size < WS_TOTAL) {
    void* p = nullptr;
    hipGetSymbolAddress(&p, HIP_SYMBOL(g_ws));
    base = (char*)p;
  }

  ushort_t* Ap  = (ushort_t*)(base + OFF_AP);
  ushort_t* Bt  = (ushort_t*)(base + OFF_BT);
  float*    XG  = (float*)(base + OFF_XG);
  ushort_t* WRP = (ushort_t*)(base + OFF_WRP);
  ushort_t* HF  = (ushort_t*)(base + OFF_HF);
  int*      BARR= (int*)(base + OFF_BARR);

  dim3 tb32x8(32, 8, 1);

  // recurrent-weight split transpose: Wr [512][2048] -> Wr' [2048][1536]
  splitBT<<<dim3(16,64), tb32x8, 0, stream>>>(Wr1f, WRP,              2048, 2048, 1536);
  splitBT<<<dim3(16,64), tb32x8, 0, stream>>>(Wr1b, WRP + 3145728,    2048, 2048, 1536);
  splitBT<<<dim3(16,64), tb32x8, 0, stream>>>(Wr2f, WRP + 2*3145728,  2048, 2048, 1536);
  splitBT<<<dim3(16,64), tb32x8, 0, stream>>>(Wr2b, WRP + 3*3145728,  2048, 2048, 1536);

  // ---- layer 1 ----
  splitA<<<14400, 256, 0, stream>>>(x, Ap, 3686400LL);                       // K=576 -> 1728
  splitBT<<<dim3(18,64), tb32x8, 0, stream>>>(Wk1f, Bt,               2048, 2048, 1728);
  splitBT<<<dim3(18,64), tb32x8, 0, stream>>>(Wk1b, Bt + 2048LL*1728, 2048, 2048, 1728);
  gemm_split<<<dim3(32,200), 256, 0, stream>>>(Ap, Bt, XG, b1f, b1b, 1728, 0);
  hipMemsetAsync(base + OFF_HF, 0, WS_TOTAL - OFF_HF, stream);
  lstm_layer<<<256, 256, 0, stream>>>(XG, WRP, lens, Ap, HF, BARR);          // writes H1 triplets

  // ---- layer 2 ----
  splitBT<<<dim3(32,64), tb32x8, 0, stream>>>(Wk2f, Bt,               2048, 2048, 3072);
  splitBT<<<dim3(32,64), tb32x8, 0, stream>>>(Wk2b, Bt + 2048LL*3072, 2048, 2048, 3072);
  gemm_split<<<dim3(32,200), 256, 0, stream>>>(Ap, Bt, XG, b2f, b2b, 3072, 0);
  hipMemsetAsync(base + OFF_HF, 0, WS_TOTAL - OFF_HF, stream);
  lstm_layer<<<256, 256, 0, stream>>>(XG, WRP + 2*3145728, lens, Ap, HF, BARR); // writes H2 triplets

  // ---- projection ----
  splitBT<<<dim3(32,4), tb32x8, 0, stream>>>(pW, Bt, 80, 80, 3072);          // pad N to 128
  gemm_split<<<dim3(1,200), 256, 0, stream>>>(Ap, Bt, out, pb, nullptr, 3072, 1);
}

// Round 11
// 10105.714 us; speedup vs baseline: 4.6457x; 1.0199x over previous
//
#include <hip/hip_runtime.h>
#include <hip/hip_bf16.h>

#define TT 800
#define BB 32

typedef unsigned short ushort_t;
using bf16x8 = __attribute__((ext_vector_type(8))) short;
using f32x4  = __attribute__((ext_vector_type(4))) float;

// ---------------- workspace layout ----------------
#define OFF_AP   0ULL                  // 25600*3072*2   = 157286400
#define OFF_BT   157286400ULL          // 4096*3072*2    =  25165824
#define OFF_XG   182452224ULL          // 2*800*32*2048*4= 419430400
#define OFF_WRP  601882624ULL          // 4*2048*1536*2  =  25165824
#define OFF_HF   627048448ULL          // 4*49152*2      =    393216
#define OFF_BARR 627441664ULL          // 32768 (flags 256*64B)
#define WS_TOTAL 627474432ULL

// Static fallback workspace: allocated at module load => graph-capture safe.
__device__ char g_ws[WS_TOTAL];

// ---------------- helpers ----------------
__device__ __forceinline__ ushort_t bf_hi(float v) {
  __hip_bfloat16 h = __float2bfloat16(v);
  return __builtin_bit_cast(ushort_t, h);
}
__device__ __forceinline__ float bf_f(ushort_t u) {
  __hip_bfloat16 h = __builtin_bit_cast(__hip_bfloat16, u);
  return __bfloat162float(h);
}
__device__ __forceinline__ float sigf(float x)      { return 1.0f / (1.0f + __expf(-x)); }
__device__ __forceinline__ float tanh_fast(float x) { return 2.0f / (1.0f + __expf(-2.0f*x)) - 1.0f; }

__device__ __forceinline__ void gload16(const void* g, void* l) {
  __builtin_amdgcn_global_load_lds((const __attribute__((address_space(1))) void*)g,
                                   (__attribute__((address_space(3))) void*)l,
                                   16, 0, 0);
}
// system-coherent direct-to-LDS load: SC0|SC1 = 0x11 -> bypass L1/L2, read L3
__device__ __forceinline__ void gload16_sys(const void* g, void* l) {
  __builtin_amdgcn_global_load_lds((const __attribute__((address_space(1))) void*)g,
                                   (__attribute__((address_space(3))) void*)l,
                                   16, 0, 17);
}
// system-coherent 2B store: write-through past L2 to L3 (no wbl2 needed)
__device__ __forceinline__ void store_short_sys(ushort_t* p, ushort_t v) {
  unsigned int vv = v;
  asm volatile("global_store_short %0, %1, off sc0 sc1" :: "v"(p), "v"(vv) : "memory");
}

// ---------------- fp32 -> (hi,lo,hi) bf16 K-interleave for A ----------------
__global__ __launch_bounds__(256) void splitA(const float* __restrict__ src,
                                              ushort_t* __restrict__ dst,
                                              long long total) {
  long long idx = (long long)blockIdx.x * 256 + threadIdx.x;
  if (idx >= total) return;
  float4 v = ((const float4*)src)[idx];
  float vs[4] = {v.x, v.y, v.z, v.w};
  ushort_t o[12];
#pragma unroll
  for (int e = 0; e < 4; ++e) {
    ushort_t hi = bf_hi(vs[e]);
    ushort_t lo = bf_hi(vs[e] - bf_f(hi));
    o[3*e] = hi; o[3*e+1] = lo; o[3*e+2] = hi;
  }
  ushort4* dp = (ushort4*)(dst + 12*idx);
  dp[0] = make_ushort4(o[0], o[1], o[2], o[3]);
  dp[1] = make_ushort4(o[4], o[5], o[6], o[7]);
  dp[2] = make_ushort4(o[8], o[9], o[10], o[11]);
}

// ---------------- fp32 [K][N] -> bf16 [n][3K] transposed split for B ----------------
__global__ __launch_bounds__(256) void splitBT(const float* __restrict__ src,
                                               ushort_t* __restrict__ dst,
                                               int srcPitch, int Nvalid, int dstPitch) {
  __shared__ float tile[32][33];
  int k0 = blockIdx.x * 32, n0 = blockIdx.y * 32;
  int tx = threadIdx.x, ty = threadIdx.y;   // (32,8)
#pragma unroll
  for (int i = 0; i < 4; ++i) {
    int k = k0 + ty + i*8;
    int n = n0 + tx;
    float v = 0.f;
    if (n < Nvalid) v = src[(long long)k * srcPitch + n];
    tile[ty + i*8][tx] = v;
  }
  __syncthreads();
#pragma unroll
  for (int q = 0; q < 4; ++q) {
    int kk = ty*4 + q;
    float v = tile[kk][tx];
    ushort_t hi = bf_hi(v);
    ushort_t lo = bf_hi(v - bf_f(hi));
    long long off = (long long)(n0 + tx) * dstPitch + 3*(k0 + kk);
    dst[off] = hi; dst[off+1] = hi; dst[off+2] = lo;
  }
}

// ---------------- split-bf16 GEMM (m97-style, 128x128 tile, BK=32) ----------------
// XCD-chunked block swizzle: chunked mapping gives each XCD a contiguous
// M-band so an A-panel loads into one XCD's L2 once and is reused by all its
// N-blocks. Bijective when nwg%8==0 (6400 and 200 qualify); identity otherwise.
__global__ __launch_bounds__(256) void gemm_split(
    const ushort_t* __restrict__ A, const ushort_t* __restrict__ Bt,
    float* __restrict__ out, const float* __restrict__ bias0,
    const float* __restrict__ bias1, int Kp, int mode)
{
  __shared__ ushort_t As[128*32];
  __shared__ ushort_t Bs[128*32];
  const int tid  = threadIdx.x;
  const int lane = tid & 63, wid = tid >> 6;

  int lid = blockIdx.y * gridDim.x + blockIdx.x;
  const int nwg = gridDim.x * gridDim.y;
  if ((nwg & 7) == 0) { const int cpx = nwg >> 3; lid = (lid & 7) * cpx + (lid >> 3); }
  const int m0 = (lid / gridDim.x) * 128, n0 = (lid % gridDim.x) * 128;

  const int wm = (wid >> 1) * 64, wn = (wid & 1) * 64;
  const int frow = lane & 15, fkg = (lane >> 4) * 8;

  f32x4 acc[4][4] = {};

  for (int k0 = 0; k0 < Kp; k0 += 32) {
#pragma unroll
    for (int i = 0; i < 2; ++i) {
      int c = tid + i*256;
      int r = c >> 2, co = (c & 3) * 8;
      gload16(A  + (size_t)(m0 + r) * Kp + k0 + co, (void*)(As + c*8));
      gload16(Bt + (size_t)(n0 + r) * Kp + k0 + co, (void*)(Bs + c*8));
    }
    __syncthreads();
    bf16x8 af[4], bq[4];
#pragma unroll
    for (int f = 0; f < 4; ++f) {
      af[f] = *(const bf16x8*)(As + (wm + f*16 + frow)*32 + fkg);
      bq[f] = *(const bf16x8*)(Bs + (wn + f*16 + frow)*32 + fkg);
    }
#pragma unroll
    for (int mf = 0; mf < 4; ++mf)
#pragma unroll
      for (int nf = 0; nf < 4; ++nf)
        acc[mf][nf] = __builtin_amdgcn_mfma_f32_16x16x32_bf16(af[mf], bq[nf], acc[mf][nf], 0, 0, 0);
    __syncthreads();
  }

  const int r4 = (lane >> 4) * 4, ccol = lane & 15;
#pragma unroll
  for (int mf = 0; mf < 4; ++mf)
#pragma unroll
    for (int nf = 0; nf < 4; ++nf) {
#pragma unroll
      for (int j = 0; j < 4; ++j) {
        int m = m0 + wm + mf*16 + r4 + j;
        int n = n0 + wn + nf*16 + ccol;
        float v = acc[mf][nf][j];
        int t = m % TT, b = m / TT;
        if (mode == 0) {
          int d2 = n >> 11, n2 = n & 2047, g = n2 >> 9, u2 = n2 & 511;
          v += (d2 == 0 ? bias0[n2] : bias1[n2]);
          out[(((size_t)d2*TT + t)*BB + b)*2048 + u2*4 + g] = v;
        } else {
          if (n < 80) out[(size_t)m*80 + n] = v + bias0[n];
        }
      }
    }
}

// ---------------- persistent bidirectional LSTM layer (MFMA recurrence) ----------------
// 256 WGs x 256 thr, 1 WG/CU. WG w: dir d=w>>7, unit-block u0=(w&127)*4.
// Cross-WG exchange via memory-side L3 (sc0sc1 write-through stores, sc0sc1
// global_load_lds, relaxed system-scope flags, no fences on the fast path).
// Direct peer polling: every WG's wave0 polls all 128 flags of its direction
// (2/lane); removes the master->sense->spinner L3 hop chain. xv prefetch in
// the poll window so its HBM latency is off the pre-flag vmcnt(0) drain.
#define SPIN_LIMIT 16384
__global__ __launch_bounds__(256, 2) void lstm_layer(
    const float* __restrict__ xg, const ushort_t* __restrict__ wrp,
    const int* __restrict__ lens, ushort_t* __restrict__ Aout,
    ushort_t* __restrict__ hfrag, int* __restrict__ barr)
{
  const int w   = blockIdx.x;
  const int d   = w >> 7;
  const int u0  = (w & 127) * 4;
  const int tid = threadIdx.x;
  const int q    = tid >> 6;         // wave = K'-quarter
  const int lane = tid & 63;
  const int c    = lane & 15;        // local col 0..15 (g=c>>2, j=c&3)
  const int kg   = lane >> 4;        // k-subgroup 0..3
  const int gc   = (c >> 2) * 512 + u0 + (c & 3);

  __shared__ ushort_t stage[4][24][512]; // 98304B: [wave][ktile(M0:0-11,M1:12-23)][lane*8]
  __shared__ float pz[32][16][5];        // [b][c][kq-partial] (+1 pad)
  __shared__ float cbuf[32][4];
  __shared__ float hpb[32][4];
  __shared__ int   lenS[32];

  if (tid < 32)  lenS[tid] = lens[tid];
  if (tid < 128) { cbuf[tid >> 2][tid & 3] = 0.f; hpb[tid >> 2][tid & 3] = 0.f; }

  // ---- load weight B-fragments once: wave q holds K'-range [384q, 384q+384) ----
  bf16x8 wfrag[12];
  {
    const ushort_t* wr = wrp + (size_t)d * 2048 * 1536 + (size_t)gc * 1536;
#pragma unroll
    for (int ktl = 0; ktl < 12; ++ktl)
      wfrag[ktl] = *(const bf16x8*)(wr + (12*q + ktl)*32 + kg*8);
  }
  __syncthreads();

  // barrier region: flags[w] @ barr[w*16] (64B stride). Direct peer poll:
  // wave0 of every WG polls its direction's 128 flags, 2 per lane.
  int* myflag = barr + w*16;
  int* pf0 = barr + (d*128 + lane)*16;
  int* pf1 = barr + (d*128 + 64 + lane)*16;

  // gate-phase thread mapping (tid<128): b2, j, global unit u
  const int b2 = tid >> 2, j = tid & 3;
  const int u  = u0 + j;
  // prefetch xv for step 0
  float4 xv = {0.f,0.f,0.f,0.f};
  if (tid < 128) {
    const int t0 = d ? (TT-1) : 0;
    xv = *(const float4*)(xg + (((size_t)d*TT + t0)*BB + b2)*2048 + (size_t)u*4);
  }

  for (int s = 0; s < TT; ++s) {
    const int t = d ? (TT - 1 - s) : s;
    const int cur = s & 1, nxt = cur ^ 1;

    // ---- stage h' fragments into LDS (24 async system-coherent loads, no VGPRs) ----
    const ushort_t* hf  = hfrag + (size_t)(d*2 + cur) * 49152;
    const ushort_t* p0  = hf + ((size_t)(12*q)*64 + lane)*8;
#pragma unroll
    for (int ktl = 0; ktl < 12; ++ktl) {
      gload16_sys(p0 + ktl*512,         &stage[q][ktl][lane*8]);      // M-tile 0
      gload16_sys(p0 + 24576 + ktl*512, &stage[q][12 + ktl][lane*8]); // M-tile 1
    }
    asm volatile("s_waitcnt vmcnt(0)" ::: "memory");
    __builtin_amdgcn_sched_barrier(0);

    f32x4 acc0 = {0.f,0.f,0.f,0.f}, acc1 = {0.f,0.f,0.f,0.f};
#pragma unroll
    for (int ktl = 0; ktl < 12; ++ktl) {
      bf16x8 a0 = *(const bf16x8*)&stage[q][ktl][lane*8];
      bf16x8 a1 = *(const bf16x8*)&stage[q][12 + ktl][lane*8];
      acc0 = __builtin_amdgcn_mfma_f32_16x16x32_bf16(a0, wfrag[ktl], acc0, 0, 0, 0);
      acc1 = __builtin_amdgcn_mfma_f32_16x16x32_bf16(a1, wfrag[ktl], acc1, 0, 0, 0);
    }
    // C/D: col=lane&15=c, row=kg*4+j (+16 for second M-tile)
#pragma unroll
    for (int jj = 0; jj < 4; ++jj) {
      pz[kg*4 + jj][c][q]      = acc0[jj];
      pz[16 + kg*4 + jj][c][q] = acc1[jj];
    }
    __syncthreads();

    if (tid < 128) {
      float z[4];
#pragma unroll
      for (int g = 0; g < 4; ++g) {
        const int cc = g*4 + j;
        z[g] = ((pz[b2][cc][0] + pz[b2][cc][1]) + (pz[b2][cc][2] + pz[b2][cc][3]));
      }
      const float zi = z[0] + xv.x, zf = z[1] + xv.y, zc = z[2] + xv.z, zo = z[3] + xv.w;
      const float co = cbuf[b2][j];
      const float cn = sigf(zf)*co + sigf(zi)*tanh_fast(zc);
      const float hn = sigf(zo)*tanh_fast(cn);
      const float hp = hpb[b2][j];
      const bool  mk = t < lenS[b2];
      const float h2 = mk ? hn : hp;
      const float c2 = mk ? cn : co;
      cbuf[b2][j] = c2; hpb[b2][j] = h2;

      const ushort_t hi = bf_hi(h2);
      const ushort_t lo = bf_hi(h2 - bf_f(hi));
      // split-A triplets for the next GEMM (plain cached stores; flushed at kernel end)
      {
        size_t ab = 3ULL * ((size_t)(b2*TT + t)*1024 + (d*512 + u));
        Aout[ab] = hi; Aout[ab+1] = lo; Aout[ab+2] = hi;
      }
      // h' fragment-order triplets for step s+1 (write-through to L3)
      {
        ushort_t* hfn = hfrag + (size_t)(d*2 + nxt) * 49152;
        const int r = b2 & 15, mt = b2 >> 4;
#pragma unroll
        for (int jj = 0; jj < 3; ++jj) {
          const int kp = 3*u + jj;
          const int kt = kp >> 5, kg2 = (kp >> 3) & 3, e = kp & 7;
          store_short_sys(&hfn[((size_t)(mt*48 + kt)*64 + kg2*16 + r)*8 + e],
                          (jj == 1) ? lo : hi);
        }
      }
    }
    // drain h'/Aout stores (per-wave) so the flag store below publishes them
    asm volatile("s_waitcnt vmcnt(0)" ::: "memory");
    __syncthreads();

    // ---- grid barrier: flag store + direct peer poll (no sense hop) ----
    if (tid == 0)
      __hip_atomic_store(myflag, s+1, __ATOMIC_RELAXED, __HIP_MEMORY_SCOPE_SYSTEM);
    // xv prefetch for step s+1: HBM latency hides under the poll window
    if (tid < 128) {
      const int s2 = (s + 1 < TT) ? (s + 1) : s;
      const int tn = d ? (TT - 1 - s2) : s2;
      xv = *(const float4*)(xg + (((size_t)d*TT + tn)*BB + b2)*2048 + (size_t)u*4);
    }
    if (q == 0) {
      int spin = 0;
      for (;;) {
        int f0 = __hip_atomic_load(pf0, __ATOMIC_RELAXED, __HIP_MEMORY_SCOPE_SYSTEM);
        int f1 = __hip_atomic_load(pf1, __ATOMIC_RELAXED, __HIP_MEMORY_SCOPE_SYSTEM);
        if (__all(f0 >= s+1 && f1 >= s+1)) break;
        __builtin_amdgcn_s_sleep(1);
        if (++spin >= SPIN_LIMIT) { spin = 0; __threadfence(); }  // anti-hang fallback
      }
    }
    __syncthreads();
  }
}

// ---------------- launch ----------------
extern "C" void kernel_launch(void* const* d_in, const int* in_sizes, int n_in,
                              void* d_out, int out_size, void* d_ws, size_t ws_size,
                              hipStream_t stream) {
  const float* x    = (const float*)d_in[0];
  const int*   lens = (const int*)d_in[1];
  const float* Wk1f = (const float*)d_in[2];
  const float* Wr1f = (const float*)d_in[3];
  const float* b1f  = (const float*)d_in[4];
  const float* Wk1b = (const float*)d_in[5];
  const float* Wr1b = (const float*)d_in[6];
  const float* b1b  = (const float*)d_in[7];
  const float* Wk2f = (const float*)d_in[8];
  const float* Wr2f = (const float*)d_in[9];
  const float* b2f  = (const float*)d_in[10];
  const float* Wk2b = (const float*)d_in[11];
  const float* Wr2b = (const float*)d_in[12];
  const float* b2b  = (const float*)d_in[13];
  const float* pW   = (const float*)d_in[14];
  const float* pb   = (const float*)d_in[15];
  float* out = (float*)d_out;

  char* base = (char*)d_ws;
  if (ws_size < WS_TOTAL) {
    void* p = nullptr;
    hipGetSymbolAddress(&p, HIP_SYMBOL(g_ws));
    base = (char*)p;
  }

  ushort_t* Ap  = (ushort_t*)(base + OFF_AP);
  ushort_t* Bt  = (ushort_t*)(base + OFF_BT);
  float*    XG  = (float*)(base + OFF_XG);
  ushort_t* WRP = (ushort_t*)(base + OFF_WRP);
  ushort_t* HF  = (ushort_t*)(base + OFF_HF);
  int*      BARR= (int*)(base + OFF_BARR);

  dim3 tb32x8(32, 8, 1);

  // recurrent-weight split transpose: Wr [512][2048] -> Wr' [2048][1536]
  splitBT<<<dim3(16,64), tb32x8, 0, stream>>>(Wr1f, WRP,              2048, 2048, 1536);
  splitBT<<<dim3(16,64), tb32x8, 0, stream>>>(Wr1b, WRP + 3145728,    2048, 2048, 1536);
  splitBT<<<dim3(16,64), tb32x8, 0, stream>>>(Wr2f, WRP + 2*3145728,  2048, 2048, 1536);
  splitBT<<<dim3(16,64), tb32x8, 0, stream>>>(Wr2b, WRP + 3*3145728,  2048, 2048, 1536);

  // ---- layer 1 ----
  splitA<<<14400, 256, 0, stream>>>(x, Ap, 3686400LL);                       // K=576 -> 1728
  splitBT<<<dim3(18,64), tb32x8, 0, stream>>>(Wk1f, Bt,               2048, 2048, 1728);
  splitBT<<<dim3(18,64), tb32x8, 0, stream>>>(Wk1b, Bt + 2048LL*1728, 2048, 2048, 1728);
  gemm_split<<<dim3(32,200), 256, 0, stream>>>(Ap, Bt, XG, b1f, b1b, 1728, 0);
  hipMemsetAsync(base + OFF_HF, 0, WS_TOTAL - OFF_HF, stream);
  lstm_layer<<<256, 256, 0, stream>>>(XG, WRP, lens, Ap, HF, BARR);          // writes H1 triplets

  // ---- layer 2 ----
  splitBT<<<dim3(32,64), tb32x8, 0, stream>>>(Wk2f, Bt,               2048, 2048, 3072);
  splitBT<<<dim3(32,64), tb32x8, 0, stream>>>(Wk2b, Bt + 2048LL*3072, 2048, 2048, 3072);
  gemm_split<<<dim3(32,200), 256, 0, stream>>>(Ap, Bt, XG, b2f, b2b, 3072, 0);
  hipMemsetAsync(base + OFF_HF, 0, WS_TOTAL - OFF_HF, stream);
  lstm_layer<<<256, 256, 0, stream>>>(XG, WRP + 2*3145728, lens, Ap, HF, BARR); // writes H2 triplets

  // ---- projection ----
  splitBT<<<dim3(32,4), tb32x8, 0, stream>>>(pW, Bt, 80, 80, 3072);          // pad N to 128
  gemm_split<<<dim3(1,200), 256, 0, stream>>>(Ap, Bt, out, pb, nullptr, 3072, 1);
}